// Round 11
// baseline (271.846 us; speedup 1.0000x reference)
//
#include <hip/hip_runtime.h>
#include <hip/hip_cooperative_groups.h>
#include <stdint.h>

namespace cg = cooperative_groups;

#define B_  4
#define T_  2048
#define C_  1024
#define D_  64

typedef float  f32x4  __attribute__((ext_vector_type(4)));
typedef float  f32x16 __attribute__((ext_vector_type(16)));
typedef short  s16x8  __attribute__((ext_vector_type(8)));

// softmax scale folded into Q-side weights/bias: 1/sqrt(64) * log2(e)
#define QSCALE 0.18033688011112042f

static __device__ __forceinline__ uint32_t f2bf(float f) {
  uint32_t u = __builtin_bit_cast(uint32_t, f);
  u += 0x7FFFu + ((u >> 16) & 1u);   // round-to-nearest-even
  return u >> 16;
}
static __device__ __forceinline__ uint32_t pack2bf(float a, float b) {
  return f2bf(a) | (f2bf(b) << 16);
}

// ===========================================================================
// Phase bodies as __device__ helpers, shared by the fused cooperative kernel
// and the standalone fallback kernels. All bodies verified R7-R10.
// ===========================================================================

// ---- phase 1: pack W into MFMA-A-fragment order (verified R3-R10) ----
static __device__ __forceinline__ void wconv_body(
    int g,
    const float* __restrict__ Wq, const float* __restrict__ bq,
    const float* __restrict__ Wk, const float* __restrict__ bk,
    const float* __restrict__ Wv, const float* __restrict__ bv,
    uint16_t* __restrict__ Wp, float* __restrict__ biascat) {
  if (g >= 24576) return;
  const int s32   = g / 768;
  const int rem   = g - s32 * 768;
  const int ntile = rem >> 6;
  const int l     = rem & 63;
  const int mrow  = l & 15, u = l >> 4;
  const int n     = ntile * 16 + mrow;
  const int mat   = n >> 6, col = n & 63;
  const float* W  = (mat == 0) ? Wq : ((mat == 1) ? Wk : Wv);
  const float  s  = (mat == 0) ? QSCALE : 1.0f;
  const int c0    = s32 * 32 + u * 8;
  float v[8];
#pragma unroll
  for (int j = 0; j < 8; ++j) v[j] = W[(size_t)(c0 + j) * D_ + col] * s;
  uint4 st;
  st.x = pack2bf(v[0], v[1]);
  st.y = pack2bf(v[2], v[3]);
  st.z = pack2bf(v[4], v[5]);
  st.w = pack2bf(v[6], v[7]);
  *reinterpret_cast<uint4*>(Wp + (size_t)g * 8) = st;
  if (g < 192) {
    float bb;
    if (g < 64)       bb = bq[g] * QSCALE;
    else if (g < 128) bb = bk[g - 64];
    else              bb = bv[g - 128];
    biascat[g] = bb;
  }
}

// ---- phase 2: QKV projection, BM=32 / 512 threads (verified R10) ----
// smem layout: xt = [2][4224] uint16 at 0 (16896 B); tbuf = [8][448] uint16
// at 16896 (7168 B).
static __device__ __forceinline__ void proj_body(
    int bx, int tid, char* smem,
    const float* __restrict__ x, const uint16_t* __restrict__ Wp,
    const float* __restrict__ biascat,
    uint16_t* __restrict__ Qfrag, uint16_t* __restrict__ Kfrag,
    uint16_t* __restrict__ Vfrag) {
  uint16_t* xt   = (uint16_t*)smem;
  uint16_t* tbuf = (uint16_t*)(smem + 16896);
  const int wave  = tid >> 6;
  const int lane  = tid & 63;
  const int mrow  = lane & 15;
  const int u     = lane >> 4;
  const int wn    = wave & 3;          // n-group 0..3
  const int mhalf = wave >> 2;         // m-half 0..1
  const int m0    = bx * 32;
  const int mw    = m0 + mhalf * 16;
  const int srow  = tid >> 4, scol = tid & 15;

  const float* xg = x + (size_t)(m0 + srow) * C_ + scol * 4;

  f32x4 acc[3];
#pragma unroll
  for (int i = 0; i < 3; ++i)
#pragma unroll
    for (int r = 0; r < 4; ++r) acc[i][r] = 0.f;

  float4 xv0 = *reinterpret_cast<const float4*>(xg);
  float4 xv1 = *reinterpret_cast<const float4*>(xg + 64);
  {
    uint2 w0, w1;
    w0.x = pack2bf(xv0.x, xv0.y);  w0.y = pack2bf(xv0.z, xv0.w);
    w1.x = pack2bf(xv1.x, xv1.y);  w1.y = pack2bf(xv1.z, xv1.w);
    *reinterpret_cast<uint2*>(&xt[srow * 132 + scol * 4])      = w0;
    *reinterpret_cast<uint2*>(&xt[srow * 132 + scol * 4 + 64]) = w1;
  }
  __syncthreads();

  for (int s = 0; s < 8; ++s) {
    const int cur = s & 1;
    if (s < 7) {  // prefetch next slab (overlaps the 12 MFMAs below)
      xv0 = *reinterpret_cast<const float4*>(xg + (s + 1) * 128);
      xv1 = *reinterpret_cast<const float4*>(xg + (s + 1) * 128 + 64);
    }
#pragma unroll
    for (int step = 0; step < 4; ++step) {
      const int s32 = s * 4 + step;
      s16x8 bf = *reinterpret_cast<const s16x8*>(
          &xt[cur * 4224 + (mhalf * 16 + mrow) * 132 + step * 32 + u * 8]);
      const uint16_t* wb = Wp + ((size_t)(s32 * 12 + wn * 3) * 64 + lane) * 8;
      s16x8 a0 = *reinterpret_cast<const s16x8*>(wb);
      s16x8 a1 = *reinterpret_cast<const s16x8*>(wb + 64 * 8);
      s16x8 a2 = *reinterpret_cast<const s16x8*>(wb + 128 * 8);
      acc[0] = __builtin_amdgcn_mfma_f32_16x16x32_bf16(a0, bf, acc[0], 0, 0, 0);
      acc[1] = __builtin_amdgcn_mfma_f32_16x16x32_bf16(a1, bf, acc[1], 0, 0, 0);
      acc[2] = __builtin_amdgcn_mfma_f32_16x16x32_bf16(a2, bf, acc[2], 0, 0, 0);
    }
    if (s < 7) {
      uint2 w0, w1;
      w0.x = pack2bf(xv0.x, xv0.y);  w0.y = pack2bf(xv0.z, xv0.w);
      w1.x = pack2bf(xv1.x, xv1.y);  w1.y = pack2bf(xv1.z, xv1.w);
      *reinterpret_cast<uint2*>(&xt[(cur ^ 1) * 4224 + srow * 132 + scol * 4])      = w0;
      *reinterpret_cast<uint2*>(&xt[(cur ^ 1) * 4224 + srow * 132 + scol * 4 + 64]) = w1;
      __syncthreads();
    }
  }

  const int bb = m0 >> 11;          // batch (32 | 2048 so uniform per block)
  const int mm = mw & (T_ - 1);     // wave's t offset within batch
#pragma unroll
  for (int nt = 0; nt < 3; ++nt) {
    const int nb = wn * 48 + nt * 16;
    uint16_t vals[4];
#pragma unroll
    for (int r = 0; r < 4; ++r)
      vals[r] = (uint16_t)f2bf(acc[nt][r] + biascat[nb + u * 4 + r]);
    if (nb >= 128) {
      // V -> fragment-major (verified R7/R9/R10)
      const int tg  = mm + mrow;
      const int t   = tg >> 5, rem = tg & 31;
      const int kc  = rem >> 4, hi2 = (rem >> 3) & 1, jj = rem & 7;
      uint16_t* base = Vfrag + ((size_t)(bb * 64 + t)) * 2048;
#pragma unroll
      for (int r = 0; r < 4; ++r) {
        int d = nb - 128 + u * 4 + r;
        int i = (d >> 5) * 2 + kc;
        int l = hi2 * 32 + (d & 31);
        base[i * 512 + l * 8 + jj] = vals[r];
      }
    } else {
      // Q/K: per-wave LDS transpose, then fragment-order stores
#pragma unroll
      for (int r = 0; r < 4; ++r)
        tbuf[wave * 448 + mrow * 28 + u * 4 + r] = vals[r];
      const int row = lane >> 2, qtr = lane & 3;
      uint2 v = *reinterpret_cast<const uint2*>(
          &tbuf[wave * 448 + row * 28 + qtr * 4]);
      const int m  = mw + row;
      const int e0 = (nb & 63) + qtr * 4;
      const int t  = (m & 2047) >> 5;
      const int c  = e0 >> 4, hi2 = (e0 >> 3) & 1, j0 = e0 & 7;
      uint16_t* dst = (nb < 64) ? Qfrag : Kfrag;
      *reinterpret_cast<uint2*>(
          dst + ((size_t)(bb * 64 + t)) * 2048 + c * 512 +
          (hi2 * 32 + (m & 31)) * 8 + j0) = v;
    }
  }
}

// ---- phase 3: attention + reduce fused (verified R9/R10) ----
// smem layout: wpart = float[8*2048] at 0 (65536 B); lw = float[256] at
// 65536 (1024 B); lbuf = float[32] at 66560 (128 B). Total 66688 B.
static __device__ __forceinline__ void attn_body(
    int bx, int tid, char* smem,
    const uint16_t* __restrict__ Qfrag, const uint16_t* __restrict__ Kfrag,
    const uint16_t* __restrict__ Vfrag, float* __restrict__ out) {
  float* wpart = (float*)smem;
  float* lw    = (float*)(smem + 65536);
  float* lbuf  = (float*)(smem + 66560);

  const int wave = tid >> 6;
  const int lane = tid & 63;
  const int ql   = lane & 31;
  const int hi   = lane >> 5;

  const int b   = bx & 3;
  const int qt  = 63 - (bx >> 2);    // largest jobs first

  s16x8 qf[4];
  {
    const uint16_t* qg = Qfrag + ((size_t)(b * 64 + qt)) * 2048 + lane * 8;
#pragma unroll
    for (int c = 0; c < 4; ++c)
      qf[c] = *reinterpret_cast<const s16x8*>(qg + c * 512);
  }

  f32x16 aco[2];
#pragma unroll
  for (int i = 0; i < 2; ++i)
#pragma unroll
    for (int r = 0; r < 16; ++r) aco[i][r] = 0.f;
  float lacc = 0.f;

  auto load_tile = [&](int t, s16x8* kf, s16x8* vf) {
    const uint16_t* kg = Kfrag + ((size_t)(b * 64 + t)) * 2048 + lane * 8;
#pragma unroll
    for (int c = 0; c < 4; ++c)
      kf[c] = *reinterpret_cast<const s16x8*>(kg + c * 512);
    const uint16_t* vg = Vfrag + ((size_t)(b * 64 + t)) * 2048 + lane * 8;
#pragma unroll
    for (int i = 0; i < 4; ++i)   // i = dm*2+kc
      vf[i] = *reinterpret_cast<const s16x8*>(vg + i * 512);
  };

  auto compute = [&](int t, const s16x8* kf, const s16x8* vf) {
    f32x16 sacc;
#pragma unroll
    for (int r = 0; r < 16; ++r) sacc[r] = 0.f;
#pragma unroll
    for (int c = 0; c < 4; ++c)
      sacc = __builtin_amdgcn_mfma_f32_32x32x16_bf16(kf[c], qf[c], sacc, 0, 0, 0);
    if (t == qt) {  // diagonal tile: causal mask
#pragma unroll
      for (int r = 0; r < 16; ++r) {
        const int koff = (r & 3) + 8 * (r >> 2) + 4 * hi;
        sacc[r] = (koff > ql) ? -1e30f : sacc[r];
      }
    }
    float p[16];
#pragma unroll
    for (int r = 0; r < 16; ++r) p[r] = __builtin_amdgcn_exp2f(sacc[r]);
    float s01 = (p[0] + p[1]) + (p[2] + p[3]);
    float s23 = (p[4] + p[5]) + (p[6] + p[7]);
    float s45 = (p[8] + p[9]) + (p[10] + p[11]);
    float s67 = (p[12] + p[13]) + (p[14] + p[15]);
    lacc += (s01 + s23) + (s45 + s67);

    // P -> B-frag via lane-pair exchange (ql <-> ql+32), verified R5-R10
    uint32_t A0 = pack2bf(p[0], p[1]),  A1 = pack2bf(p[2], p[3]);
    uint32_t B0 = pack2bf(p[4], p[5]),  B1 = pack2bf(p[6], p[7]);
    uint32_t C0 = pack2bf(p[8], p[9]),  C1 = pack2bf(p[10], p[11]);
    uint32_t D0 = pack2bf(p[12], p[13]), D1 = pack2bf(p[14], p[15]);
    uint32_t r0 = (uint32_t)__shfl_xor((int)(hi ? A0 : B0), 32, 64);
    uint32_t r1 = (uint32_t)__shfl_xor((int)(hi ? A1 : B1), 32, 64);
    uint32_t r2 = (uint32_t)__shfl_xor((int)(hi ? C0 : D0), 32, 64);
    uint32_t r3 = (uint32_t)__shfl_xor((int)(hi ? C1 : D1), 32, 64);
    union { uint32_t u[4]; s16x8 v; } pf0, pf1;
    pf0.u[0] = hi ? r0 : A0;  pf0.u[1] = hi ? r1 : A1;
    pf0.u[2] = hi ? B0 : r0;  pf0.u[3] = hi ? B1 : r1;
    pf1.u[0] = hi ? r2 : C0;  pf1.u[1] = hi ? r3 : C1;
    pf1.u[2] = hi ? D0 : r2;  pf1.u[3] = hi ? D1 : r3;
    aco[0] = __builtin_amdgcn_mfma_f32_32x32x16_bf16(vf[0], pf0.v, aco[0], 0, 0, 0);
    aco[1] = __builtin_amdgcn_mfma_f32_32x32x16_bf16(vf[2], pf0.v, aco[1], 0, 0, 0);
    aco[0] = __builtin_amdgcn_mfma_f32_32x32x16_bf16(vf[1], pf1.v, aco[0], 0, 0, 0);
    aco[1] = __builtin_amdgcn_mfma_f32_32x32x16_bf16(vf[3], pf1.v, aco[1], 0, 0, 0);
  };

  // register-double-buffered k-loop, stride 8 (<=8 tiles per wave)
  {
    int t = wave;
    if (t <= qt) {
      s16x8 kfA[4], vfA[4], kfB[4], vfB[4];
      load_tile(t, kfA, vfA);
      while (true) {
        int tn = t + 8;
        if (tn <= qt) load_tile(tn, kfB, vfB);
        compute(t, kfA, vfA);
        if (tn > qt) break;
        t = tn; tn = t + 8;
        if (tn <= qt) load_tile(tn, kfA, vfA);
        compute(t, kfB, vfB);
        if (tn > qt) break;
        t = tn;
      }
    }
  }

  lacc += __shfl_xor(lacc, 32, 64);

  // 8-wave LDS merge (verified R9/R10)
#pragma unroll
  for (int dm = 0; dm < 2; ++dm)
#pragma unroll
    for (int r = 0; r < 16; ++r)
      wpart[wave * 2048 + dm * 1024 + r * 64 + hi * 32 + ql] = aco[dm][r];
  if (hi == 0) lw[wave * 32 + ql] = lacc;
  __syncthreads();

  const int base = tid * 4;
  float4 s0 = {0.f, 0.f, 0.f, 0.f};
#pragma unroll
  for (int w = 0; w < 8; ++w) {
    float4 a = *reinterpret_cast<const float4*>(wpart + w * 2048 + base);
    s0.x += a.x; s0.y += a.y; s0.z += a.z; s0.w += a.w;
  }
  if (tid < 32) {
    float ls = 0.f;
#pragma unroll
    for (int w = 0; w < 8; ++w) ls += lw[w * 32 + tid];
    lbuf[tid] = 1.0f / ls;
  }
  __syncthreads();  // all wpart reads done before trans overlay

  float* trans = wpart;
  {
    const int dm = base >> 10, r = (base >> 6) & 15, h2 = (base >> 5) & 1;
    const int ql0 = base & 31;
    const int d = dm * 32 + (r & 3) + 8 * (r >> 2) + 4 * h2;
    float* tr = &trans[d * 33 + ql0];
    tr[0] = s0.x; tr[1] = s0.y; tr[2] = s0.z; tr[3] = s0.w;
  }
  __syncthreads();

  {
    const int q  = tid >> 4;
    const int dg = (tid & 15) * 4;
    const float rinv = lbuf[q];
    float4 o;
    o.x = trans[(dg + 0) * 33 + q] * rinv;
    o.y = trans[(dg + 1) * 33 + q] * rinv;
    o.z = trans[(dg + 2) * 33 + q] * rinv;
    o.w = trans[(dg + 3) * 33 + q] * rinv;
    *reinterpret_cast<float4*>(
        out + ((size_t)(b * T_ + qt * 32 + q)) * D_ + dg) = o;
  }
}

// ===========================================================================
// Fused cooperative kernel: 256 blocks x 512 threads (1 block/CU guaranteed:
// 66.7 KB LDS, <=16 waves/CU). grid.sync() between phases.
// ===========================================================================
__global__ __launch_bounds__(512) void fused_kernel(
    const float* __restrict__ x,
    const float* __restrict__ Wq, const float* __restrict__ bq,
    const float* __restrict__ Wk, const float* __restrict__ bk,
    const float* __restrict__ Wv, const float* __restrict__ bv,
    float* __restrict__ out,
    uint16_t* __restrict__ Wp, float* __restrict__ biascat,
    uint16_t* __restrict__ Qfrag, uint16_t* __restrict__ Kfrag,
    uint16_t* __restrict__ Vfrag) {
  cg::grid_group grid = cg::this_grid();
  __shared__ __align__(16) char smem[66688];
  const int tid = threadIdx.x;
  const int bx  = blockIdx.x;

  wconv_body(bx * 512 + tid, Wq, bq, Wk, bk, Wv, bv, Wp, biascat);
  __threadfence();
  grid.sync();

  proj_body(bx, tid, smem, x, Wp, biascat, Qfrag, Kfrag, Vfrag);
  __threadfence();
  grid.sync();

  attn_body(bx, tid, smem, Qfrag, Kfrag, Vfrag, out);
}

// ===========================================================================
// Standalone fallback kernels (the R10-verified 3-launch path).
// ===========================================================================
__global__ __launch_bounds__(256) void wconv_kernel(
    const float* __restrict__ Wq, const float* __restrict__ bq,
    const float* __restrict__ Wk, const float* __restrict__ bk,
    const float* __restrict__ Wv, const float* __restrict__ bv,
    uint16_t* __restrict__ Wp, float* __restrict__ biascat) {
  wconv_body(blockIdx.x * 256 + threadIdx.x, Wq, bq, Wk, bk, Wv, bv, Wp, biascat);
}

__global__ __launch_bounds__(512) void proj_kernel(
    const float* __restrict__ x, const uint16_t* __restrict__ Wp,
    const float* __restrict__ biascat,
    uint16_t* __restrict__ Qfrag, uint16_t* __restrict__ Kfrag,
    uint16_t* __restrict__ Vfrag) {
  __shared__ __align__(16) char smem[24064];
  proj_body(blockIdx.x, threadIdx.x, smem, x, Wp, biascat, Qfrag, Kfrag, Vfrag);
}

__global__ __launch_bounds__(512) void attn_kernel(
    const uint16_t* __restrict__ Qfrag, const uint16_t* __restrict__ Kfrag,
    const uint16_t* __restrict__ Vfrag, float* __restrict__ out) {
  __shared__ __align__(16) char smem[66688];
  attn_body(blockIdx.x, threadIdx.x, smem, Qfrag, Kfrag, Vfrag, out);
}

// ---------------------------------------------------------------------------
extern "C" void kernel_launch(void* const* d_in, const int* in_sizes, int n_in,
                              void* d_out, int out_size, void* d_ws, size_t ws_size,
                              hipStream_t stream) {
  (void)in_sizes; (void)n_in; (void)out_size; (void)ws_size;
  const float* x  = (const float*)d_in[0];
  const float* Wq = (const float*)d_in[1];
  const float* bq = (const float*)d_in[2];
  const float* Wk = (const float*)d_in[3];
  const float* bk = (const float*)d_in[4];
  const float* Wv = (const float*)d_in[5];
  const float* bv = (const float*)d_in[6];
  float* out = (float*)d_out;

  char* ws = (char*)d_ws;
  uint16_t* Wp      = (uint16_t*)(ws);                 // 393,216 B
  float*    biascat = (float*)(ws + 393216);           // 1,024 B (768 used)
  uint16_t* Qfrag   = (uint16_t*)(ws + 394240);        // 1,048,576 B
  uint16_t* Kfrag   = (uint16_t*)(ws + 1442816);       // 1,048,576 B
  uint16_t* Vfrag   = (uint16_t*)(ws + 2491392);       // 1,048,576 B

  void* kargs[] = {
    (void*)&x, (void*)&Wq, (void*)&bq, (void*)&Wk, (void*)&bk,
    (void*)&Wv, (void*)&bv, (void*)&out, (void*)&Wp, (void*)&biascat,
    (void*)&Qfrag, (void*)&Kfrag, (void*)&Vfrag
  };
  hipError_t err = hipLaunchCooperativeKernel(
      (const void*)fused_kernel, dim3(256), dim3(512), kargs, 0, stream);
  if (err != hipSuccess) {
    (void)hipGetLastError();  // clear sticky error; fall back to 3 launches
    hipLaunchKernelGGL(wconv_kernel, dim3(96), dim3(256), 0, stream,
                       Wq, bq, Wk, bk, Wv, bv, Wp, biascat);
    hipLaunchKernelGGL(proj_kernel, dim3(256), dim3(512), 0, stream,
                       x, Wp, biascat, Qfrag, Kfrag, Vfrag);
    hipLaunchKernelGGL(attn_kernel, dim3(256), dim3(512), 0, stream,
                       Qfrag, Kfrag, Vfrag, out);
  }
}

// Round 12
// 101.220 us; speedup vs baseline: 2.6857x; 2.6857x over previous
//
#include <hip/hip_runtime.h>
#include <stdint.h>

#define B_  4
#define T_  2048
#define C_  1024
#define D_  64

typedef float  f32x4  __attribute__((ext_vector_type(4)));
typedef float  f32x16 __attribute__((ext_vector_type(16)));
typedef short  s16x8  __attribute__((ext_vector_type(8)));

// softmax scale folded into Q-side weights/bias: 1/sqrt(64) * log2(e)
#define QSCALE 0.18033688011112042f

static __device__ __forceinline__ uint32_t f2bf(float f) {
  uint32_t u = __builtin_bit_cast(uint32_t, f);
  u += 0x7FFFu + ((u >> 16) & 1u);   // round-to-nearest-even
  return u >> 16;
}
static __device__ __forceinline__ uint32_t pack2bf(float a, float b) {
  return f2bf(a) | (f2bf(b) << 16);
}

// ---------------------------------------------------------------------------
// Kernel 1: pack W into MFMA-A-fragment order (verified R3-R10).
// ---------------------------------------------------------------------------
__global__ __launch_bounds__(256) void wconv_kernel(
    const float* __restrict__ Wq, const float* __restrict__ bq,
    const float* __restrict__ Wk, const float* __restrict__ bk,
    const float* __restrict__ Wv, const float* __restrict__ bv,
    uint16_t* __restrict__ Wp, float* __restrict__ biascat) {
  const int g = blockIdx.x * 256 + threadIdx.x;  // 0..24575
  const int s32   = g / 768;
  const int rem   = g - s32 * 768;
  const int ntile = rem >> 6;
  const int l     = rem & 63;
  const int mrow  = l & 15, u = l >> 4;
  const int n     = ntile * 16 + mrow;
  const int mat   = n >> 6, col = n & 63;
  const float* W  = (mat == 0) ? Wq : ((mat == 1) ? Wk : Wv);
  const float  s  = (mat == 0) ? QSCALE : 1.0f;
  const int c0    = s32 * 32 + u * 8;
  float v[8];
#pragma unroll
  for (int j = 0; j < 8; ++j) v[j] = W[(size_t)(c0 + j) * D_ + col] * s;
  uint4 st;
  st.x = pack2bf(v[0], v[1]);
  st.y = pack2bf(v[2], v[3]);
  st.z = pack2bf(v[4], v[5]);
  st.w = pack2bf(v[6], v[7]);
  *reinterpret_cast<uint4*>(Wp + (size_t)g * 8) = st;
  if (g < 192) {
    float bb;
    if (g < 64)       bb = bq[g] * QSCALE;
    else if (g < 128) bb = bk[g - 64];
    else              bb = bv[g - 128];
    biascat[g] = bb;
  }
}

// ---------------------------------------------------------------------------
// Kernel 2: QKV projection with fragment-major epilogue (verified R7/R9).
// ---------------------------------------------------------------------------
__global__ __launch_bounds__(256) void proj_kernel(
    const float* __restrict__ x, const uint16_t* __restrict__ Wp,
    const float* __restrict__ biascat,
    uint16_t* __restrict__ Qfrag, uint16_t* __restrict__ Kfrag,
    uint16_t* __restrict__ Vfrag) {
  __shared__ __align__(16) uint16_t xt[2][16 * 132];    // 8448 B
  __shared__ __align__(16) uint16_t tbuf[4][16 * 28];   // 3584 B
  const int tid  = threadIdx.x;
  const int wave = tid >> 6;
  const int lane = tid & 63;
  const int mrow = lane & 15;
  const int u    = lane >> 4;
  const int m0   = blockIdx.x * 16;
  const int srow = tid >> 4, scol = tid & 15;

  const float* xg = x + (size_t)(m0 + srow) * C_ + scol * 4;

  f32x4 acc[3];
#pragma unroll
  for (int i = 0; i < 3; ++i)
#pragma unroll
    for (int r = 0; r < 4; ++r) acc[i][r] = 0.f;

  float4 xv0 = *reinterpret_cast<const float4*>(xg);
  float4 xv1 = *reinterpret_cast<const float4*>(xg + 64);
  {
    uint2 w0, w1;
    w0.x = pack2bf(xv0.x, xv0.y);  w0.y = pack2bf(xv0.z, xv0.w);
    w1.x = pack2bf(xv1.x, xv1.y);  w1.y = pack2bf(xv1.z, xv1.w);
    *reinterpret_cast<uint2*>(&xt[0][srow * 132 + scol * 4])      = w0;
    *reinterpret_cast<uint2*>(&xt[0][srow * 132 + scol * 4 + 64]) = w1;
  }
  __syncthreads();

  for (int s = 0; s < 8; ++s) {
    const int cur = s & 1;
    if (s < 7) {  // prefetch next slab (overlaps the 12 MFMAs below)
      xv0 = *reinterpret_cast<const float4*>(xg + (s + 1) * 128);
      xv1 = *reinterpret_cast<const float4*>(xg + (s + 1) * 128 + 64);
    }
#pragma unroll
    for (int step = 0; step < 4; ++step) {
      const int s32 = s * 4 + step;
      s16x8 bf = *reinterpret_cast<const s16x8*>(
          &xt[cur][mrow * 132 + step * 32 + u * 8]);
      const uint16_t* wb = Wp + ((size_t)(s32 * 12 + wave * 3) * 64 + lane) * 8;
      s16x8 a0 = *reinterpret_cast<const s16x8*>(wb);
      s16x8 a1 = *reinterpret_cast<const s16x8*>(wb + 64 * 8);
      s16x8 a2 = *reinterpret_cast<const s16x8*>(wb + 128 * 8);
      acc[0] = __builtin_amdgcn_mfma_f32_16x16x32_bf16(a0, bf, acc[0], 0, 0, 0);
      acc[1] = __builtin_amdgcn_mfma_f32_16x16x32_bf16(a1, bf, acc[1], 0, 0, 0);
      acc[2] = __builtin_amdgcn_mfma_f32_16x16x32_bf16(a2, bf, acc[2], 0, 0, 0);
    }
    if (s < 7) {
      uint2 w0, w1;
      w0.x = pack2bf(xv0.x, xv0.y);  w0.y = pack2bf(xv0.z, xv0.w);
      w1.x = pack2bf(xv1.x, xv1.y);  w1.y = pack2bf(xv1.z, xv1.w);
      *reinterpret_cast<uint2*>(&xt[cur ^ 1][srow * 132 + scol * 4])      = w0;
      *reinterpret_cast<uint2*>(&xt[cur ^ 1][srow * 132 + scol * 4 + 64]) = w1;
      __syncthreads();
    }
  }

  const int bb = m0 >> 11;         // batch
  const int mm = m0 & (T_ - 1);    // t offset within batch
#pragma unroll
  for (int nt = 0; nt < 3; ++nt) {
    const int nb = wave * 48 + nt * 16;
    uint16_t vals[4];
#pragma unroll
    for (int r = 0; r < 4; ++r)
      vals[r] = (uint16_t)f2bf(acc[nt][r] + biascat[nb + u * 4 + r]);
    if (nb >= 128) {
      // V -> fragment-major (verified R7/R9)
      const int tg  = mm + mrow;
      const int t   = tg >> 5, rem = tg & 31;
      const int kc  = rem >> 4, hi2 = (rem >> 3) & 1, jj = rem & 7;
      uint16_t* base = Vfrag + ((size_t)(bb * 64 + t)) * 2048;
#pragma unroll
      for (int r = 0; r < 4; ++r) {
        int d = nb - 128 + u * 4 + r;
        int i = (d >> 5) * 2 + kc;
        int l = hi2 * 32 + (d & 31);
        base[i * 512 + l * 8 + jj] = vals[r];
      }
    } else {
      // Q/K: per-wave LDS transpose, then fragment-order stores (R7)
#pragma unroll
      for (int r = 0; r < 4; ++r)
        tbuf[wave][mrow * 28 + u * 4 + r] = vals[r];
      const int row = lane >> 2, qtr = lane & 3;
      uint2 v = *reinterpret_cast<const uint2*>(&tbuf[wave][row * 28 + qtr * 4]);
      const int m  = m0 + row;
      const int e0 = (nb & 63) + qtr * 4;
      const int t  = (m & 2047) >> 5;
      const int c  = e0 >> 4, hi2 = (e0 >> 3) & 1, j0 = e0 & 7;
      uint16_t* dst = (nb < 64) ? Qfrag : Kfrag;
      *reinterpret_cast<uint2*>(
          dst + ((size_t)(bb * 64 + t)) * 2048 + c * 512 +
          (hi2 * 32 + (m & 31)) * 8 + j0) = v;
    }
  }
}

// ---------------------------------------------------------------------------
// Kernel 3: attention + reduce fused (verified R9, the 101.76 us optimum).
// One block per (b,qt): 256 blocks x 512 threads (8 waves), stride-8
// k-interleave, LDS merge, normalize in-block, write out directly.
// slot(dm,r,hi,ql) = dm*1024 + r*64 + hi*32 + ql.
// ---------------------------------------------------------------------------
__global__ __launch_bounds__(512) void attn_kernel(
    const uint16_t* __restrict__ Qfrag, const uint16_t* __restrict__ Kfrag,
    const uint16_t* __restrict__ Vfrag, float* __restrict__ out) {
  __shared__ float wpart[8 * 2048];   // 65536 B (trans overlays after merge)
  __shared__ float lw[8 * 32];        // 1024 B
  __shared__ float lbuf[32];          // 128 B

  const int tid  = threadIdx.x;       // 0..511
  const int wave = tid >> 6;          // 0..7
  const int lane = tid & 63;
  const int ql   = lane & 31;
  const int hi   = lane >> 5;

  const int blk = blockIdx.x;         // 256 = 64 qt x 4 b
  const int b   = blk & 3;
  const int qt  = 63 - (blk >> 2);    // largest jobs first

  // Q fragments: coalesced 16B/lane (verified R7)
  s16x8 qf[4];
  {
    const uint16_t* qg = Qfrag + ((size_t)(b * 64 + qt)) * 2048 + lane * 8;
#pragma unroll
    for (int c = 0; c < 4; ++c)
      qf[c] = *reinterpret_cast<const s16x8*>(qg + c * 512);
  }

  f32x16 aco[2];
#pragma unroll
  for (int i = 0; i < 2; ++i)
#pragma unroll
    for (int r = 0; r < 16; ++r) aco[i][r] = 0.f;
  float lacc = 0.f;

  auto load_tile = [&](int t, s16x8* kf, s16x8* vf) {
    const uint16_t* kg = Kfrag + ((size_t)(b * 64 + t)) * 2048 + lane * 8;
#pragma unroll
    for (int c = 0; c < 4; ++c)
      kf[c] = *reinterpret_cast<const s16x8*>(kg + c * 512);
    const uint16_t* vg = Vfrag + ((size_t)(b * 64 + t)) * 2048 + lane * 8;
#pragma unroll
    for (int i = 0; i < 4; ++i)   // i = dm*2+kc
      vf[i] = *reinterpret_cast<const s16x8*>(vg + i * 512);
  };

  auto compute = [&](int t, const s16x8* kf, const s16x8* vf) {
    f32x16 sacc;
#pragma unroll
    for (int r = 0; r < 16; ++r) sacc[r] = 0.f;
#pragma unroll
    for (int c = 0; c < 4; ++c)
      sacc = __builtin_amdgcn_mfma_f32_32x32x16_bf16(kf[c], qf[c], sacc, 0, 0, 0);
    if (t == qt) {  // diagonal tile: causal mask
#pragma unroll
      for (int r = 0; r < 16; ++r) {
        const int koff = (r & 3) + 8 * (r >> 2) + 4 * hi;
        sacc[r] = (koff > ql) ? -1e30f : sacc[r];
      }
    }
    float p[16];
#pragma unroll
    for (int r = 0; r < 16; ++r) p[r] = __builtin_amdgcn_exp2f(sacc[r]);
    float s01 = (p[0] + p[1]) + (p[2] + p[3]);
    float s23 = (p[4] + p[5]) + (p[6] + p[7]);
    float s45 = (p[8] + p[9]) + (p[10] + p[11]);
    float s67 = (p[12] + p[13]) + (p[14] + p[15]);
    lacc += (s01 + s23) + (s45 + s67);

    // P -> B-frag via lane-pair exchange (ql <-> ql+32), verified R5-R10
    uint32_t A0 = pack2bf(p[0], p[1]),  A1 = pack2bf(p[2], p[3]);
    uint32_t B0 = pack2bf(p[4], p[5]),  B1 = pack2bf(p[6], p[7]);
    uint32_t C0 = pack2bf(p[8], p[9]),  C1 = pack2bf(p[10], p[11]);
    uint32_t D0 = pack2bf(p[12], p[13]), D1 = pack2bf(p[14], p[15]);
    uint32_t r0 = (uint32_t)__shfl_xor((int)(hi ? A0 : B0), 32, 64);
    uint32_t r1 = (uint32_t)__shfl_xor((int)(hi ? A1 : B1), 32, 64);
    uint32_t r2 = (uint32_t)__shfl_xor((int)(hi ? C0 : D0), 32, 64);
    uint32_t r3 = (uint32_t)__shfl_xor((int)(hi ? C1 : D1), 32, 64);
    union { uint32_t u[4]; s16x8 v; } pf0, pf1;
    pf0.u[0] = hi ? r0 : A0;  pf0.u[1] = hi ? r1 : A1;
    pf0.u[2] = hi ? B0 : r0;  pf0.u[3] = hi ? B1 : r1;
    pf1.u[0] = hi ? r2 : C0;  pf1.u[1] = hi ? r3 : C1;
    pf1.u[2] = hi ? D0 : r2;  pf1.u[3] = hi ? D1 : r3;
    aco[0] = __builtin_amdgcn_mfma_f32_32x32x16_bf16(vf[0], pf0.v, aco[0], 0, 0, 0);
    aco[1] = __builtin_amdgcn_mfma_f32_32x32x16_bf16(vf[2], pf0.v, aco[1], 0, 0, 0);
    aco[0] = __builtin_amdgcn_mfma_f32_32x32x16_bf16(vf[1], pf1.v, aco[0], 0, 0, 0);
    aco[1] = __builtin_amdgcn_mfma_f32_32x32x16_bf16(vf[3], pf1.v, aco[1], 0, 0, 0);
  };

  // register-double-buffered k-loop, stride 8 (<=8 tiles per wave)
  {
    int t = wave;
    if (t <= qt) {
      s16x8 kfA[4], vfA[4], kfB[4], vfB[4];
      load_tile(t, kfA, vfA);
      while (true) {
        int tn = t + 8;
        if (tn <= qt) load_tile(tn, kfB, vfB);
        compute(t, kfA, vfA);
        if (tn > qt) break;
        t = tn; tn = t + 8;
        if (tn <= qt) load_tile(tn, kfA, vfA);
        compute(t, kfB, vfB);
        if (tn > qt) break;
        t = tn;
      }
    }
  }

  lacc += __shfl_xor(lacc, 32, 64);

  // 8-wave LDS merge (verified R9)
#pragma unroll
  for (int dm = 0; dm < 2; ++dm)
#pragma unroll
    for (int r = 0; r < 16; ++r)
      wpart[wave * 2048 + dm * 1024 + r * 64 + hi * 32 + ql] = aco[dm][r];
  if (hi == 0) lw[wave * 32 + ql] = lacc;
  __syncthreads();

  // merge 8 waves in slot space: 512 threads x 4 slots
  const int base = tid * 4;
  float4 s0 = {0.f, 0.f, 0.f, 0.f};
#pragma unroll
  for (int w = 0; w < 8; ++w) {
    float4 a = *reinterpret_cast<const float4*>(wpart + w * 2048 + base);
    s0.x += a.x; s0.y += a.y; s0.z += a.z; s0.w += a.w;
  }
  if (tid < 32) {
    float ls = 0.f;
#pragma unroll
    for (int w = 0; w < 8; ++w) ls += lw[w * 32 + tid];
    lbuf[tid] = 1.0f / ls;
  }
  __syncthreads();  // all wpart reads done before trans overlay

  // slot decode -> trans[d][q] (overlay on wpart)
  float* trans = wpart;
  {
    const int dm = base >> 10, r = (base >> 6) & 15, h2 = (base >> 5) & 1;
    const int ql0 = base & 31;
    const int d = dm * 32 + (r & 3) + 8 * (r >> 2) + 4 * h2;
    float* tr = &trans[d * 33 + ql0];
    tr[0] = s0.x; tr[1] = s0.y; tr[2] = s0.z; tr[3] = s0.w;
  }
  __syncthreads();

  // normalize + write out: 512 threads x 4 elems, [q][d] coalesced
  {
    const int q  = tid >> 4;
    const int dg = (tid & 15) * 4;
    const float rinv = lbuf[q];
    float4 o;
    o.x = trans[(dg + 0) * 33 + q] * rinv;
    o.y = trans[(dg + 1) * 33 + q] * rinv;
    o.z = trans[(dg + 2) * 33 + q] * rinv;
    o.w = trans[(dg + 3) * 33 + q] * rinv;
    *reinterpret_cast<float4*>(
        out + ((size_t)(b * T_ + qt * 32 + q)) * D_ + dg) = o;
  }
}

// ---------------------------------------------------------------------------
extern "C" void kernel_launch(void* const* d_in, const int* in_sizes, int n_in,
                              void* d_out, int out_size, void* d_ws, size_t ws_size,
                              hipStream_t stream) {
  (void)in_sizes; (void)n_in; (void)out_size; (void)ws_size;
  const float* x  = (const float*)d_in[0];
  const float* Wq = (const float*)d_in[1];
  const float* bq = (const float*)d_in[2];
  const float* Wk = (const float*)d_in[3];
  const float* bk = (const float*)d_in[4];
  const float* Wv = (const float*)d_in[5];
  const float* bv = (const float*)d_in[6];
  float* out = (float*)d_out;

  char* ws = (char*)d_ws;
  uint16_t* Wp      = (uint16_t*)(ws);                 // 393,216 B
  float*    biascat = (float*)(ws + 393216);           // 1,024 B (768 used)
  uint16_t* Qfrag   = (uint16_t*)(ws + 394240);        // 1,048,576 B
  uint16_t* Kfrag   = (uint16_t*)(ws + 1442816);       // 1,048,576 B
  uint16_t* Vfrag   = (uint16_t*)(ws + 2491392);       // 1,048,576 B

  hipLaunchKernelGGL(wconv_kernel, dim3(96), dim3(256), 0, stream,
                     Wq, bq, Wk, bk, Wv, bv, Wp, biascat);
  hipLaunchKernelGGL(proj_kernel, dim3(512), dim3(256), 0, stream,
                     x, Wp, biascat, Qfrag, Kfrag, Vfrag);
  hipLaunchKernelGGL(attn_kernel, dim3(256), dim3(512), 0, stream,
                     Qfrag, Kfrag, Vfrag, out);
}